// Round 1
// baseline (348.323 us; speedup 1.0000x reference)
//
#include <hip/hip_runtime.h>
#include <math.h>

#define C  2048
#define L  4096
#define L2 2048
#define CW3 6144  // C*3

// ---- small arrays in d_ws (float offsets, all multiples of 16) ----
constexpr size_t OFF_RS_A = 0;      // 2048  row sums of input
constexpr size_t OFF_RQ_A = 2048;   // 2048  row sumsq of input
constexpr size_t OFF_RS_B = 4096;   // 2048  row sums of insum
constexpr size_t OFF_RQ_B = 6144;   // 2048  row sumsq of insum
constexpr size_t OFF_SCAL = 8192;   // 16    [0]=meanA [1]=coefA [2]=meanB [3]=coefB [4]=sum(fc_b)
constexpr size_t OFF_CW   = 8208;   // 2048  colsum(fc_w)
constexpr size_t OFF_S    = 10256;  // 2048  s = fc_w@rx + 2048*fc_b
constexpr size_t OFF_V    = 12304;  // 2048
constexpr size_t OFF_O2   = 14352;  // 2048  out2 raw
constexpr size_t OFF_MIX  = 16400;  // 2048  out_mix
constexpr size_t OFF_OV   = 18448;  // 2048  final per-row gate
constexpr size_t OFF_U    = 20496;  // 6144
constexpr size_t OFF_G    = 26640;  // 6144
constexpr size_t OFF_H    = 32784;  // 6144
// total 38928 floats = 152 KB

// ---- big scratch staged in d_out (fully overwritten by k8 at the end) ----
constexpr size_t SC_CWP  = 0;        // 32*2048
constexpr size_t SC_GP   = 65536;    // 32*6144
constexpr size_t SC_HP   = 262144;   // 32*6144
constexpr size_t SC_VP   = 458752;   // 32*2048
constexpr size_t SC_O2P  = 524288;   // 32*2048
constexpr size_t SC_WC   = 589824;   // 2048*2048 compacted conv1_w[:,:,1]
// end 4784128 < out_size 8388608

__device__ __forceinline__ float wredf(float v) {
#pragma unroll
  for (int o = 32; o; o >>= 1) v += __shfl_down(v, o, 64);
  return v;
}

__device__ __forceinline__ float sigm(float x) { return 1.f / (1.f + expf(-x)); }

// K1: per-row sum & sumsq of input and insum
__global__ void k1_rowstats(const float* __restrict__ A, const float* __restrict__ B,
                            float* __restrict__ ws) {
  __shared__ float l1[4], l2[4];
  const float* src = blockIdx.y ? B : A;
  float* rs = ws + (blockIdx.y ? OFF_RS_B : OFF_RS_A);
  float* rq = ws + (blockIdx.y ? OFF_RQ_B : OFF_RQ_A);
  int row = blockIdx.x;
  const float4* p = (const float4*)(src + (size_t)row * L);
  float s = 0.f, q = 0.f;
  for (int i = threadIdx.x; i < L / 4; i += 256) {
    float4 v = p[i];
    s += (v.x + v.y) + (v.z + v.w);
    q += (v.x * v.x + v.y * v.y) + (v.z * v.z + v.w * v.w);
  }
  s = wredf(s); q = wredf(q);
  int lane = threadIdx.x & 63, w = threadIdx.x >> 6;
  if (!lane) { l1[w] = s; l2[w] = q; }
  __syncthreads();
  if (!threadIdx.x) {
    rs[row] = l1[0] + l1[1] + l1[2] + l1[3];
    rq[row] = l2[0] + l2[1] + l2[2] + l2[3];
  }
}

// K_scalars: simam coefficients + sum(fc_b)
__global__ void k_scalars(const float* __restrict__ fc_b, float* __restrict__ ws) {
  __shared__ double red[256];
  const float* srcs[5] = { ws + OFF_RS_A, ws + OFF_RQ_A, ws + OFF_RS_B, ws + OFF_RQ_B, fc_b };
  double res[5];
  for (int a = 0; a < 5; ++a) {
    double acc = 0;
    for (int i = threadIdx.x; i < 2048; i += 256) acc += (double)srcs[a][i];
    red[threadIdx.x] = acc;
    __syncthreads();
    for (int st = 128; st; st >>= 1) {
      if (threadIdx.x < st) red[threadIdx.x] += red[threadIdx.x + st];
      __syncthreads();
    }
    res[a] = red[0];
    __syncthreads();
  }
  if (!threadIdx.x) {
    const double N = (double)C * (double)L;
    const double n = N - 1.0;
    double meanA = res[0] / N, meanB = res[2] / N;
    double dA = res[1] - res[0] * res[0] / N;
    double dB = res[3] - res[2] * res[2] / N;
    float* sc = ws + OFF_SCAL;
    sc[0] = (float)meanA;
    sc[1] = (float)(1.0 / (4.0 * (dA / n + 1e-4)));
    sc[2] = (float)meanB;
    sc[3] = (float)(1.0 / (4.0 * (dB / n + 1e-4)));
    sc[4] = (float)res[4];
  }
}

// K2a: s[o] = sum_i fc_w[o,i]*rx[i] + L2*fc_b[o], rx = rowsum(input)/2
__global__ void k2a_s(const float* __restrict__ fc_w, const float* __restrict__ fc_b,
                      float* __restrict__ ws) {
  __shared__ float l[4];
  int o = blockIdx.x;
  const float4* w = (const float4*)(fc_w + (size_t)o * C);
  const float4* rx = (const float4*)(ws + OFF_RS_A);
  float acc = 0.f;
  for (int i = threadIdx.x; i < C / 4; i += 256) {
    float4 a = w[i], r = rx[i];
    acc += a.x * r.x + a.y * r.y + a.z * r.z + a.w * r.w;
  }
  acc = wredf(acc);
  int lane = threadIdx.x & 63, wv = threadIdx.x >> 6;
  if (!lane) l[wv] = acc;
  __syncthreads();
  if (!threadIdx.x)
    (ws + OFF_S)[o] = 0.5f * (l[0] + l[1] + l[2] + l[3]) + (float)L2 * fc_b[o];
}

// K2b/K2c: cw[i] = colsum of fc_w (two-stage)
__global__ void k2b_cwpart(const float* __restrict__ fc_w, float* __restrict__ sc) {
  int col = blockIdx.x * 256 + threadIdx.x;
  int r0 = blockIdx.y * 64;
  const float* p = fc_w + (size_t)r0 * C + col;
  float acc = 0.f;
  for (int k = 0; k < 64; ++k) acc += p[(size_t)k * C];
  (sc + SC_CWP)[blockIdx.y * C + col] = acc;
}

__global__ void k2c_cw(const float* __restrict__ sc, float* __restrict__ ws) {
  int i = blockIdx.x * 256 + threadIdx.x;
  float acc = 0.f;
  for (int br = 0; br < 32; ++br) acc += (sc + SC_CWP)[br * C + i];
  (ws + OFF_CW)[i] = acc;
}

// K3: g[c,t] = sum_i cw[i]*w[i,c,t]; h[c,t] = sum_i s[i]*w[i,c,t]; also compact mid-tap
__global__ void k3_gh(const float* __restrict__ conv1_w, float* __restrict__ ws,
                      float* __restrict__ sc) {
  __shared__ float lcw[64], ls[64];
  int col = blockIdx.x * 256 + threadIdx.x;  // [0, 6144)
  int i0 = blockIdx.y * 64;
  if (threadIdx.x < 64) {
    lcw[threadIdx.x] = (ws + OFF_CW)[i0 + threadIdx.x];
    ls[threadIdx.x] = (ws + OFF_S)[i0 + threadIdx.x];
  }
  __syncthreads();
  const float* base = conv1_w + (size_t)i0 * CW3 + col;
  float* wc = sc + SC_WC;
  int cmod = col % 3, cdiv = col / 3;
  float ag = 0.f, ah = 0.f;
  for (int k = 0; k < 64; ++k) {
    float wv = base[(size_t)k * CW3];
    ag += lcw[k] * wv;
    ah += ls[k] * wv;
    if (cmod == 1) wc[(size_t)(i0 + k) * C + cdiv] = wv;
  }
  (sc + SC_GP)[blockIdx.y * CW3 + col] = ag;
  (sc + SC_HP)[blockIdx.y * CW3 + col] = ah;
}

__global__ void k3b_gh(const float* __restrict__ sc, float* __restrict__ ws) {
  int j = blockIdx.x * 256 + threadIdx.x;
  float ag = 0.f, ah = 0.f;
  for (int br = 0; br < 32; ++br) {
    ag += (sc + SC_GP)[br * CW3 + j];
    ah += (sc + SC_HP)[br * CW3 + j];
  }
  (ws + OFF_G)[j] = ag;
  (ws + OFF_H)[j] = ah;
}

// K4: v[k] (partials) and out2raw[k] (partials) from insum
__global__ void k4_vpart(const float* __restrict__ insum, const float* __restrict__ ws,
                         float* __restrict__ sc) {
  __shared__ float xm[258];
  int t = threadIdx.x;
  int k0 = blockIdx.x * 256;
  int c0 = blockIdx.y * 64;
  const float* g = ws + OFF_G;
  const float* h = ws + OFF_H;
  float accv = 0.f, acco = 0.f;
  for (int c = c0; c < c0 + 64; ++c) {
    for (int jj = t; jj < 258; jj += 256) {
      int j = k0 - 1 + jj;
      float val = 0.f;
      if (j >= 0 && j < L2) {
        float2 ab = *(const float2*)(insum + (size_t)c * L + 2 * j);
        val = (ab.x + ab.y) * 0.5f;
      }
      xm[jj] = val;
    }
    __syncthreads();
    float g0 = g[c * 3], g1 = g[c * 3 + 1], g2 = g[c * 3 + 2];
    float h0 = h[c * 3], h1 = h[c * 3 + 1], h2 = h[c * 3 + 2];
    float xl = xm[t], xc = xm[t + 1], xr = xm[t + 2];
    accv += g0 * xl + g1 * xc + g2 * xr;
    acco += h0 * xl + h1 * xc + h2 * xr;
    __syncthreads();
  }
  (sc + SC_VP)[blockIdx.y * L2 + k0 + t] = accv;
  (sc + SC_O2P)[blockIdx.y * L2 + k0 + t] = acco;
}

__global__ void k4b_v(const float* __restrict__ sc, float* __restrict__ ws) {
  int k = blockIdx.x * 256 + threadIdx.x;
  float av = 0.f, ao = 0.f;
  for (int br = 0; br < 32; ++br) {
    av += (sc + SC_VP)[br * L2 + k];
    ao += (sc + SC_O2P)[br * L2 + k];
  }
  (ws + OFF_V)[k] = av + (ws + OFF_SCAL)[4];  // + sum(fc_b)
  (ws + OFF_O2)[k] = ao;
}

// K5: U[c,t] = sum_j x[c,j]*v[j+1-t'] correlations
__global__ void k5_U(const float* __restrict__ input, float* __restrict__ ws) {
  __shared__ float l0[4], l1[4], l2s[4];
  int c = blockIdx.x;
  const float* v = ws + OFF_V;
  float a0 = 0.f, a1 = 0.f, a2 = 0.f;
  for (int j = threadIdx.x; j < L2; j += 256) {
    float2 ab = *(const float2*)(input + (size_t)c * L + 2 * j);
    float xmv = (ab.x + ab.y) * 0.5f;
    float vp = (j + 1 < L2) ? v[j + 1] : 0.f;
    float vc = v[j];
    float vm = j ? v[j - 1] : 0.f;
    a0 += xmv * vp;
    a1 += xmv * vc;
    a2 += xmv * vm;
  }
  a0 = wredf(a0); a1 = wredf(a1); a2 = wredf(a2);
  int lane = threadIdx.x & 63, w = threadIdx.x >> 6;
  if (!lane) { l0[w] = a0; l1[w] = a1; l2s[w] = a2; }
  __syncthreads();
  if (!threadIdx.x) {
    (ws + OFF_U)[c * 3 + 0] = l0[0] + l0[1] + l0[2] + l0[3];
    (ws + OFF_U)[c * 3 + 1] = l1[0] + l1[1] + l1[2] + l1[3];
    (ws + OFF_U)[c * 3 + 2] = l2s[0] + l2s[1] + l2s[2] + l2s[3];
  }
}

// K6: out1[a] = sum conv1_w[a,:,:]*U; out_mix = sig(out1)*mf + sig(out2)*(1-mf)
__global__ void k6_out1(const float* __restrict__ conv1_w, const float* __restrict__ mix_w,
                        float* __restrict__ ws) {
  __shared__ float l[4];
  int a = blockIdx.x;
  const float4* w4 = (const float4*)(conv1_w + (size_t)a * CW3);
  const float4* u4 = (const float4*)(ws + OFF_U);
  float acc = 0.f;
  for (int m = threadIdx.x; m < CW3 / 4; m += 256) {
    float4 wv = w4[m], uv = u4[m];
    acc += wv.x * uv.x + wv.y * uv.y + wv.z * uv.z + wv.w * uv.w;
  }
  acc = wredf(acc);
  int lane = threadIdx.x & 63, w = threadIdx.x >> 6;
  if (!lane) l[w] = acc;
  __syncthreads();
  if (!threadIdx.x) {
    float mfv = sigm(mix_w[0]);
    float o1 = sigm(l[0] + l[1] + l[2] + l[3]);
    float o2 = sigm((ws + OFF_O2)[a]);
    (ws + OFF_MIX)[a] = o1 * mfv + o2 * (1.f - mfv);
  }
}

// K7: ov[o] = sig( sum_i conv1_w[o,i,1]*out_mix[i] ) via compacted Wc
__global__ void k7_ov(const float* __restrict__ sc, float* __restrict__ ws) {
  __shared__ float l[4];
  int o = blockIdx.x;
  const float4* w4 = (const float4*)(sc + SC_WC + (size_t)o * C);
  const float4* m4 = (const float4*)(ws + OFF_MIX);
  float acc = 0.f;
  for (int i = threadIdx.x; i < C / 4; i += 256) {
    float4 wv = w4[i], mv = m4[i];
    acc += wv.x * mv.x + wv.y * mv.y + wv.z * mv.z + wv.w * mv.w;
  }
  acc = wredf(acc);
  int lane = threadIdx.x & 63, w = threadIdx.x >> 6;
  if (!lane) l[w] = acc;
  __syncthreads();
  if (!threadIdx.x) (ws + OFF_OV)[o] = sigm(l[0] + l[1] + l[2] + l[3]);
}

__device__ __forceinline__ float simam1(float x, float m, float cf) {
  float d = x - m;
  float y = d * d * cf + 0.5f;
  return x * (1.f + 1.f / (1.f + expf(-y)));
}

// K8: final elementwise — overwrites all of d_out (incl. scratch regions)
__global__ void k8_final(const float* __restrict__ input, const float* __restrict__ insum,
                         float* __restrict__ out, const float* __restrict__ ws) {
  int c = blockIdx.x;
  size_t base = (size_t)c * L + (size_t)blockIdx.y * (L / 2);
  const float4* pa = (const float4*)(input + base);
  const float4* pb = (const float4*)(insum + base);
  float4* po = (float4*)(out + base);
  const float* scal = ws + OFF_SCAL;
  float mA = scal[0], cA = scal[1], mB = scal[2], cB = scal[3];
  float ovc = (ws + OFF_OV)[c];
  for (int i = threadIdx.x; i < L / 8; i += 256) {
    float4 a = pa[i], b = pb[i], r;
    r.x = (simam1(a.x, mA, cA) * 0.6f + simam1(b.x, mB, cB) * 0.4f) * ovc;
    r.y = (simam1(a.y, mA, cA) * 0.6f + simam1(b.y, mB, cB) * 0.4f) * ovc;
    r.z = (simam1(a.z, mA, cA) * 0.6f + simam1(b.z, mB, cB) * 0.4f) * ovc;
    r.w = (simam1(a.w, mA, cA) * 0.6f + simam1(b.w, mB, cB) * 0.4f) * ovc;
    po[i] = r;
  }
}

extern "C" void kernel_launch(void* const* d_in, const int* in_sizes, int n_in,
                              void* d_out, int out_size, void* d_ws, size_t ws_size,
                              hipStream_t stream) {
  const float* input   = (const float*)d_in[0];
  const float* insum   = (const float*)d_in[1];
  const float* conv1_w = (const float*)d_in[2];
  const float* fc_w    = (const float*)d_in[3];
  const float* fc_b    = (const float*)d_in[4];
  const float* mix_w   = (const float*)d_in[5];
  float* out = (float*)d_out;
  float* ws  = (float*)d_ws;
  float* sc  = out;  // big partials staged in d_out; k8 overwrites everything

  dim3 b(256);
  k1_rowstats<<<dim3(C, 2), b, 0, stream>>>(input, insum, ws);
  k2b_cwpart<<<dim3(8, 32), b, 0, stream>>>(fc_w, sc);
  k2c_cw<<<8, b, 0, stream>>>(sc, ws);
  k_scalars<<<1, b, 0, stream>>>(fc_b, ws);
  k2a_s<<<C, b, 0, stream>>>(fc_w, fc_b, ws);
  k3_gh<<<dim3(24, 32), b, 0, stream>>>(conv1_w, ws, sc);
  k3b_gh<<<24, b, 0, stream>>>(sc, ws);
  k4_vpart<<<dim3(8, 32), b, 0, stream>>>(insum, ws, sc);
  k4b_v<<<8, b, 0, stream>>>(sc, ws);
  k5_U<<<C, b, 0, stream>>>(input, ws);
  k6_out1<<<C, b, 0, stream>>>(conv1_w, mix_w, ws);
  k7_ov<<<C, b, 0, stream>>>(sc, ws);
  k8_final<<<dim3(C, 2), b, 0, stream>>>(input, insum, out, ws);
}

// Round 2
// 243.654 us; speedup vs baseline: 1.4296x; 1.4296x over previous
//
#include <hip/hip_runtime.h>
#include <math.h>

#define C  2048
#define L  4096
#define L2 2048
#define CW3 6144  // C*3

// ---- small arrays in d_ws (float offsets) ----
constexpr size_t OFF_RS_A = 0;      // 2048
constexpr size_t OFF_RQ_A = 2048;   // 2048
constexpr size_t OFF_RS_B = 4096;   // 2048
constexpr size_t OFF_RQ_B = 6144;   // 2048
constexpr size_t OFF_SCAL = 8192;   // 16: [0]=meanA [1]=coefA [2]=meanB [3]=coefB [4]=sum(fc_b)
constexpr size_t OFF_CW   = 8208;   // 2048 colsum(fc_w)
constexpr size_t OFF_S    = 10256;  // 2048
constexpr size_t OFF_V    = 12304;  // 2048 (atomic-accumulated, NO bias)
constexpr size_t OFF_O2   = 14352;  // 2048 (contiguous after V)
constexpr size_t OFF_MIX  = 16400;  // 2048
constexpr size_t OFF_OV   = 18448;  // 2048
constexpr size_t OFF_U    = 20496;  // 6144
constexpr size_t OFF_G    = 26640;  // 6144 (atomic; zeroed in kB)
constexpr size_t OFF_H    = 32784;  // 6144 (contiguous after G)

// ---- big scratch staged in d_out (fully overwritten by k8) ----
constexpr size_t SC_CWP = 0;        // 32*2048
constexpr size_t SC_VP  = 65536;    // 256*2048  layout [cblk][k]
constexpr size_t SC_O2P = 589824;   // 256*2048
// end 1114112 floats < out_size 8388608

__device__ __forceinline__ float wredf(float v) {
#pragma unroll
  for (int o = 32; o; o >>= 1) v += __shfl_down(v, o, 64);
  return v;
}
__device__ __forceinline__ double wredd(double v) {
#pragma unroll
  for (int o = 32; o; o >>= 1) v += __shfl_down(v, o, 64);
  return v;
}
__device__ __forceinline__ float sigm(float x) { return 1.f / (1.f + expf(-x)); }

// ===== kA: rowstats (4096 blocks) + fc_w colsum partials (256 blocks) =====
__global__ void kA(const float* __restrict__ A, const float* __restrict__ B,
                   const float* __restrict__ fc_w, float* __restrict__ ws,
                   float* __restrict__ sc) {
  int bx = blockIdx.x;
  if (bx < 4096) {
    __shared__ float l1[4], l2[4];
    const float* src = (bx < 2048) ? A : B;
    int row = (bx < 2048) ? bx : bx - 2048;
    float* rs = ws + ((bx < 2048) ? OFF_RS_A : OFF_RS_B);
    float* rq = ws + ((bx < 2048) ? OFF_RQ_A : OFF_RQ_B);
    const float4* p = (const float4*)(src + (size_t)row * L);
    float s = 0.f, q = 0.f;
#pragma unroll
    for (int i = threadIdx.x; i < L / 4; i += 256) {
      float4 v = p[i];
      s += (v.x + v.y) + (v.z + v.w);
      q += (v.x * v.x + v.y * v.y) + (v.z * v.z + v.w * v.w);
    }
    s = wredf(s); q = wredf(q);
    int lane = threadIdx.x & 63, w = threadIdx.x >> 6;
    if (!lane) { l1[w] = s; l2[w] = q; }
    __syncthreads();
    if (!threadIdx.x) {
      rs[row] = l1[0] + l1[1] + l1[2] + l1[3];
      rq[row] = l2[0] + l2[1] + l2[2] + l2[3];
    }
  } else {
    int cb = bx - 4096;                 // 0..255
    int col = (cb & 7) * 256 + threadIdx.x;
    int r0 = (cb >> 3) * 64;
    const float* p = fc_w + (size_t)r0 * C + col;
    float acc = 0.f;
#pragma unroll 8
    for (int k = 0; k < 64; ++k) acc += p[(size_t)k * C];
    (sc + SC_CWP)[(cb >> 3) * C + col] = acc;
  }
}

// ===== kB: s (2048) + cw final (8) + scalars (1) + zero G/H (6) =====
__global__ void kB(const float* __restrict__ fc_w, const float* __restrict__ fc_b,
                   float* __restrict__ ws, const float* __restrict__ sc) {
  int bx = blockIdx.x;
  if (bx < 2048) {
    __shared__ float l[4];
    int o = bx;
    const float4* w = (const float4*)(fc_w + (size_t)o * C);
    const float4* rx = (const float4*)(ws + OFF_RS_A);
    float acc = 0.f;
#pragma unroll
    for (int i = threadIdx.x; i < C / 4; i += 256) {
      float4 a = w[i], r = rx[i];
      acc += a.x * r.x + a.y * r.y + a.z * r.z + a.w * r.w;
    }
    acc = wredf(acc);
    int lane = threadIdx.x & 63, wv = threadIdx.x >> 6;
    if (!lane) l[wv] = acc;
    __syncthreads();
    if (!threadIdx.x)
      (ws + OFF_S)[o] = 0.5f * (l[0] + l[1] + l[2] + l[3]) + (float)L2 * fc_b[o];
  } else if (bx < 2056) {
    int i = (bx - 2048) * 256 + threadIdx.x;
    float acc = 0.f;
#pragma unroll
    for (int br = 0; br < 32; ++br) acc += (sc + SC_CWP)[br * C + i];
    (ws + OFF_CW)[i] = acc;
  } else if (bx == 2056) {
    // scalars: wave w reduces array w; wave 0 also fc_b
    __shared__ double sd[5];
    int lane = threadIdx.x & 63, w = threadIdx.x >> 6;
    const float* arr = ws + (w == 0 ? OFF_RS_A : w == 1 ? OFF_RQ_A
                                                        : w == 2 ? OFF_RS_B : OFF_RQ_B);
    double acc = 0.0, accb = 0.0;
    for (int i = lane; i < 2048; i += 64) {
      acc += (double)arr[i];
      if (w == 0) accb += (double)fc_b[i];
    }
    acc = wredd(acc);
    if (w == 0) accb = wredd(accb);
    if (!lane) { sd[w] = acc; if (w == 0) sd[4] = accb; }
    __syncthreads();
    if (!threadIdx.x) {
      const double N = (double)C * (double)L, n = N - 1.0;
      double dA = sd[1] - sd[0] * sd[0] / N;
      double dB = sd[3] - sd[2] * sd[2] / N;
      float* s = ws + OFF_SCAL;
      s[0] = (float)(sd[0] / N);
      s[1] = (float)(1.0 / (4.0 * (dA / n + 1e-4)));
      s[2] = (float)(sd[2] / N);
      s[3] = (float)(1.0 / (4.0 * (dB / n + 1e-4)));
      s[4] = (float)sd[4];
    }
  } else {
    // zero G/H (12288 contiguous floats at OFF_G)
    size_t base = (size_t)(bx - 2057) * 2048;
#pragma unroll
    for (int j = 0; j < 8; ++j) ws[OFF_G + base + threadIdx.x + j * 256] = 0.f;
  }
}

// ===== k3: g/h via atomics (24x64 worker blocks) + zero V/O2 (by==64) =====
__global__ void k3_gh(const float* __restrict__ conv1_w, float* __restrict__ ws) {
  if (blockIdx.y == 64) {
    if (blockIdx.x < 16) {
      int idx = blockIdx.x * 256 + threadIdx.x;  // 0..4095 covers V(2048)+O2(2048)
      ws[OFF_V + idx] = 0.f;
    }
    return;
  }
  __shared__ float lcw[32], ls[32];
  int col = blockIdx.x * 256 + threadIdx.x;  // [0, 6144)
  int i0 = blockIdx.y * 32;
  if (threadIdx.x < 32) {
    lcw[threadIdx.x] = (ws + OFF_CW)[i0 + threadIdx.x];
    ls[threadIdx.x] = (ws + OFF_S)[i0 + threadIdx.x];
  }
  __syncthreads();
  const float* base = conv1_w + (size_t)i0 * CW3 + col;
  float ag = 0.f, ah = 0.f;
#pragma unroll 8
  for (int k = 0; k < 32; ++k) {
    float wv = base[(size_t)k * CW3];
    ag += lcw[k] * wv;
    ah += ls[k] * wv;
  }
  atomicAdd(ws + OFF_G + col, ag);
  atomicAdd(ws + OFF_H + col, ah);
}

// ===== k4: v/o2 partials; grid (8 k-tiles, 256 c-tiles of 8 ch), no smem =====
__global__ void k4_vpart(const float* __restrict__ insum, const float* __restrict__ ws,
                         float* __restrict__ sc) {
  int k = blockIdx.x * 256 + threadIdx.x;  // [0, 2048)
  int c0 = blockIdx.y * 8;
  const float* g = ws + OFF_G;
  const float* h = ws + OFF_H;
  float accv = 0.f, acco = 0.f;
#pragma unroll
  for (int c = c0; c < c0 + 8; ++c) {
    const float* row = insum + (size_t)c * L;
    float2 bm = *(const float2*)(row + 2 * k);
    float xc = (bm.x + bm.y) * 0.5f;
    float xl = 0.f, xr = 0.f;
    if (k > 0) {
      float2 am = *(const float2*)(row + 2 * k - 2);
      xl = (am.x + am.y) * 0.5f;
    }
    if (k < L2 - 1) {
      float2 dm = *(const float2*)(row + 2 * k + 2);
      xr = (dm.x + dm.y) * 0.5f;
    }
    accv += g[c * 3] * xl + g[c * 3 + 1] * xc + g[c * 3 + 2] * xr;
    acco += h[c * 3] * xl + h[c * 3 + 1] * xc + h[c * 3 + 2] * xr;
  }
  (sc + SC_VP)[(size_t)blockIdx.y * L2 + k] = accv;   // [cblk][k]: coalesced
  (sc + SC_O2P)[(size_t)blockIdx.y * L2 + k] = acco;
}

// ===== k4b: reduce 256 partials, 4-way split + atomics =====
__global__ void k4b_v(const float* __restrict__ sc, float* __restrict__ ws) {
  int k = blockIdx.x * 256 + threadIdx.x;
  int p0 = blockIdx.y * 64;
  float av = 0.f, ao = 0.f;
#pragma unroll 8
  for (int p = p0; p < p0 + 64; ++p) {
    av += (sc + SC_VP)[(size_t)p * L2 + k];
    ao += (sc + SC_O2P)[(size_t)p * L2 + k];
  }
  atomicAdd(ws + OFF_V + k, av);
  atomicAdd(ws + OFF_O2 + k, ao);
}

// ===== k5: U[c,0..2] correlations; bias sum(fc_b) folded into v reads =====
__global__ void k5_U(const float* __restrict__ input, float* __restrict__ ws) {
  __shared__ float l0[4], l1[4], l2s[4];
  int c = blockIdx.x;
  const float* v = ws + OFF_V;
  float sb = (ws + OFF_SCAL)[4];
  float a0 = 0.f, a1 = 0.f, a2 = 0.f;
  for (int j = threadIdx.x; j < L2; j += 256) {
    float2 ab = *(const float2*)(input + (size_t)c * L + 2 * j);
    float xmv = (ab.x + ab.y) * 0.5f;
    float vp = (j + 1 < L2) ? v[j + 1] + sb : 0.f;
    float vc = v[j] + sb;
    float vm = j ? v[j - 1] + sb : 0.f;
    a0 += xmv * vp;
    a1 += xmv * vc;
    a2 += xmv * vm;
  }
  a0 = wredf(a0); a1 = wredf(a1); a2 = wredf(a2);
  int lane = threadIdx.x & 63, w = threadIdx.x >> 6;
  if (!lane) { l0[w] = a0; l1[w] = a1; l2s[w] = a2; }
  __syncthreads();
  if (!threadIdx.x) {
    (ws + OFF_U)[c * 3 + 0] = l0[0] + l0[1] + l0[2] + l0[3];
    (ws + OFF_U)[c * 3 + 1] = l1[0] + l1[1] + l1[2] + l1[3];
    (ws + OFF_U)[c * 3 + 2] = l2s[0] + l2s[1] + l2s[2] + l2s[3];
  }
}

// ===== k6: out1 + mix =====
__global__ void k6_out1(const float* __restrict__ conv1_w, const float* __restrict__ mix_w,
                        float* __restrict__ ws) {
  __shared__ float l[4];
  int a = blockIdx.x;
  const float4* w4 = (const float4*)(conv1_w + (size_t)a * CW3);
  const float4* u4 = (const float4*)(ws + OFF_U);
  float acc = 0.f;
#pragma unroll
  for (int m = threadIdx.x; m < CW3 / 4; m += 256) {
    float4 wv = w4[m], uv = u4[m];
    acc += wv.x * uv.x + wv.y * uv.y + wv.z * uv.z + wv.w * uv.w;
  }
  acc = wredf(acc);
  int lane = threadIdx.x & 63, w = threadIdx.x >> 6;
  if (!lane) l[w] = acc;
  __syncthreads();
  if (!threadIdx.x) {
    float mfv = sigm(mix_w[0]);
    float o1 = sigm(l[0] + l[1] + l[2] + l[3]);
    float o2 = sigm((ws + OFF_O2)[a]);
    (ws + OFF_MIX)[a] = o1 * mfv + o2 * (1.f - mfv);
  }
}

// ===== k7: ov via mid-taps, 12-float periods read as 3 aligned float4 =====
__global__ void k7_ov(const float* __restrict__ conv1_w, float* __restrict__ ws) {
  __shared__ float l[4];
  int a = blockIdx.x;
  const float4* w4 = (const float4*)(conv1_w + (size_t)a * CW3);
  const float4* m4 = (const float4*)(ws + OFF_MIX);
  float acc = 0.f;
#pragma unroll
  for (int p = threadIdx.x; p < 512; p += 256) {
    float4 f0 = w4[3 * p], f1 = w4[3 * p + 1], f2 = w4[3 * p + 2];
    float4 m = m4[p];
    acc += f0.y * m.x + f1.x * m.y + f1.w * m.z + f2.z * m.w;
  }
  acc = wredf(acc);
  int lane = threadIdx.x & 63, w = threadIdx.x >> 6;
  if (!lane) l[w] = acc;
  __syncthreads();
  if (!threadIdx.x) (ws + OFF_OV)[a] = sigm(l[0] + l[1] + l[2] + l[3]);
}

__device__ __forceinline__ float simam1(float x, float m, float cf) {
  float d = x - m;
  float y = d * d * cf + 0.5f;
  return x * (1.f + 1.f / (1.f + expf(-y)));
}

// ===== k8: final elementwise — overwrites all of d_out =====
__global__ void k8_final(const float* __restrict__ input, const float* __restrict__ insum,
                         float* __restrict__ out, const float* __restrict__ ws) {
  int c = blockIdx.x;
  size_t base = (size_t)c * L + (size_t)blockIdx.y * (L / 2);
  const float4* pa = (const float4*)(input + base);
  const float4* pb = (const float4*)(insum + base);
  float4* po = (float4*)(out + base);
  const float* scal = ws + OFF_SCAL;
  float mA = scal[0], cA = scal[1], mB = scal[2], cB = scal[3];
  float ovc = (ws + OFF_OV)[c];
#pragma unroll
  for (int i = threadIdx.x; i < L / 8; i += 256) {
    float4 a = pa[i], b = pb[i], r;
    r.x = (simam1(a.x, mA, cA) * 0.6f + simam1(b.x, mB, cB) * 0.4f) * ovc;
    r.y = (simam1(a.y, mA, cA) * 0.6f + simam1(b.y, mB, cB) * 0.4f) * ovc;
    r.z = (simam1(a.z, mA, cA) * 0.6f + simam1(b.z, mB, cB) * 0.4f) * ovc;
    r.w = (simam1(a.w, mA, cA) * 0.6f + simam1(b.w, mB, cB) * 0.4f) * ovc;
    po[i] = r;
  }
}

extern "C" void kernel_launch(void* const* d_in, const int* in_sizes, int n_in,
                              void* d_out, int out_size, void* d_ws, size_t ws_size,
                              hipStream_t stream) {
  const float* input   = (const float*)d_in[0];
  const float* insum   = (const float*)d_in[1];
  const float* conv1_w = (const float*)d_in[2];
  const float* fc_w    = (const float*)d_in[3];
  const float* fc_b    = (const float*)d_in[4];
  const float* mix_w   = (const float*)d_in[5];
  float* out = (float*)d_out;
  float* ws  = (float*)d_ws;
  float* sc  = out;  // big partials staged in d_out; k8 overwrites everything

  dim3 b(256);
  kA<<<4352, b, 0, stream>>>(input, insum, fc_w, ws, sc);
  kB<<<2063, b, 0, stream>>>(fc_w, fc_b, ws, sc);
  k3_gh<<<dim3(24, 65), b, 0, stream>>>(conv1_w, ws);
  k4_vpart<<<dim3(8, 256), b, 0, stream>>>(insum, ws, sc);
  k4b_v<<<dim3(8, 4), b, 0, stream>>>(sc, ws);
  k5_U<<<C, b, 0, stream>>>(input, ws);
  k6_out1<<<C, b, 0, stream>>>(conv1_w, mix_w, ws);
  k7_ov<<<C, b, 0, stream>>>(conv1_w, ws);
  k8_final<<<dim3(C, 2), b, 0, stream>>>(input, insum, out, ws);
}